// Round 4
// baseline (208.525 us; speedup 1.0000x reference)
//
#include <hip/hip_runtime.h>

// Spatial transformer: affine grid-sample, reflect padding, bilinear.
// x: (B=32, C=3, H=512, W=512) fp32; p: (B,4) fp32 = [tx, ty, theta, scale].
//
// R4: kernel was VALU-instruction-bound (~455 VALU/px from counters).
//  - reflect is piecewise-linear slope +-1 -> block-uniform fold test; fast
//    path = 1 fma + 1 med3 clamp per axis per pixel (slow path ~7% of waves).
//  - one LDS index per pixel; all 12 gathers via immediate offsets
//    (i00, +1, +36, +37, + ch*1188). x1/y1 clamps removed by zero-padding
//    LDS col 32..35 and row 32 (pads only ever touched with weight == 0).
//  - 32-bit offsets off uniform bases for staging + stores; no fmodf.

#define B_ 32
#define C_ 3
#define H_ 512
#define W_ 512
#define LSTRIDE 36
#define CH_WORDS (33 * LSTRIDE)   // 1188 words per channel (32 rows + pad row)
#define PLANE (H_ * W_)           // 262144

__device__ __forceinline__ float reflect_unclipped(float u) {
    float c = fabsf(u + 0.5f);
    float flips = floorf(c * (1.0f / 512.0f));      // /512 exact (pow2)
    float extra = fmaf(flips, -512.0f, c);
    float half = flips * 0.5f;
    float par = half - floorf(half);                // 0 or 0.5
    float v = (par == 0.0f) ? extra : (512.0f - extra);
    return v - 0.5f;
}

__device__ __forceinline__ float reflect_clipped(float u) {
    float v = reflect_unclipped(u);
    return fminf(fmaxf(v, 0.0f), 511.0f);
}

__global__ __launch_bounds__(256)
void st_kernel(const float* __restrict__ x, const float* __restrict__ p,
               float* __restrict__ out) {
    __shared__ float smem[C_ * CH_WORDS];           // 14256 B

    const int tid = threadIdx.x;
    const int b   = blockIdx.z;                     // uniform -> scalar loads

    const float tx = p[b * 4 + 0];
    const float ty = p[b * 4 + 1];
    const float th = p[b * 4 + 2];
    const float ts = p[b * 4 + 3];
    float sth, cth;
    sincosf(th, &sth, &cth);
    const float a  =  ts * cth;
    const float bq = -ts * sth;
    const float d  =  ts * sth;
    const float e  =  ts * cth;
    // ix_pre = a*col + bq*row + Cx (algebraic expansion of the reference map)
    const float Cx = fmaf(256.0f, tx, 255.5f) - 255.5f * (a + bq);
    const float Cy = fmaf(256.0f, ty, 255.5f) - 255.5f * (d + e);

    // ---- block-uniform: pre-image range, fold test, box ----
    const float c0 = (float)(blockIdx.x << 4);
    const float r0 = (float)(blockIdx.y << 4);

    const float ax0 = a * c0,  ax1 = a * (c0 + 15.0f);
    const float bx0v = bq * r0, bx1v = bq * (r0 + 15.0f);
    const float u1x = fminf(ax0, ax1) + fminf(bx0v, bx1v) + Cx;
    const float u2x = fmaxf(ax0, ax1) + fmaxf(bx0v, bx1v) + Cx;

    const float dy0 = d * c0,  dy1 = d * (c0 + 15.0f);
    const float ey0 = e * r0,  ey1 = e * (r0 + 15.0f);
    const float u1y = fminf(dy0, dy1) + fminf(ey0, ey1) + Cy;
    const float u2y = fmaxf(dy0, dy1) + fmaxf(ey0, ey1) + Cy;

    const float r1x = reflect_unclipped(u1x);
    const float r2x = reflect_unclipped(u2x);
    const float r1y = reflect_unclipped(u1y);
    const float r2y = reflect_unclipped(u2y);
    const bool fastx = fabsf(r2x - r1x) >= (u2x - u1x) - 0.01f;
    const bool fasty = fabsf(r2y - r1y) >= (u2y - u1y) - 0.01f;
    const float sxs = (r2x >= r1x) ? 1.0f : -1.0f;
    const float sys = (r2y >= r1y) ? 1.0f : -1.0f;

    const float rcx = reflect_clipped(0.5f * (u1x + u2x));
    const float rcy = reflect_clipped(0.5f * (u1y + u2y));
    const float extx = 8.0f * (fabsf(a) + fabsf(bq)) + 3.0f;
    const float exty = 8.0f * (fabsf(d) + fabsf(e)) + 3.0f;
    int bx0 = min(max((int)floorf(rcx - extx), 0), W_ - 32) & ~3;
    int by0 = min(max((int)floorf(rcy - exty), 0), H_ - 32);
    const float bx0f = (float)bx0;
    const float by0f = (float)by0;
    const float cxo = r1x - sxs * u1x - bx0f;   // fast: xl = sxs*ixp + cxo
    const float cyo = r1y - sys * u1y - by0f;
    const float xhi = 511.0f - bx0f;
    const float yhi = 511.0f - by0f;

    // ---- stage 32x32 x 3ch into LDS (3 float4/thread) + zero pads ----
    {
        const int srow = tid >> 3;             // 0..31
        const int scol = (tid & 7) << 2;       // 0..28
        const int gidx = ((by0 + srow) << 9) + bx0 + scol;
        const float* gp = x + (size_t)b * (C_ * PLANE) + gidx;
        const float4 v0 = *(const float4*)(gp);
        const float4 v1 = *(const float4*)(gp + PLANE);
        const float4 v2 = *(const float4*)(gp + 2 * PLANE);
        const int l = srow * LSTRIDE + scol;
        *(float4*)&smem[l] = v0;
        *(float4*)&smem[CH_WORDS + l] = v1;
        *(float4*)&smem[2 * CH_WORDS + l] = v2;
        // pads: per ch, 33 row-tail float4s (cols 32..35) + 8 float4s of row 32
        if (tid < 123) {
            const int ch = tid / 41;
            const int rp = tid - ch * 41;
            const int off = (rp < 33) ? (rp * LSTRIDE + 32)
                                      : (32 * LSTRIDE + ((rp - 33) << 2));
            *(float4*)&smem[ch * CH_WORDS + off] = make_float4(0.f, 0.f, 0.f, 0.f);
        }
    }
    __syncthreads();

    // ---- per-pixel ----
    const int lcol = tid & 15;
    const int lrow = tid >> 4;
    const float colf = c0 + (float)lcol;
    const float rowf = r0 + (float)lrow;
    const float ixp = fmaf(a, colf, fmaf(bq, rowf, Cx));
    const float iyp = fmaf(d, colf, fmaf(e, rowf, Cy));

    float xl, yl;
    if (fastx) xl = fminf(fmaxf(fmaf(sxs, ixp, cxo), 0.0f), xhi);
    else       xl = reflect_clipped(ixp) - bx0f;
    if (fasty) yl = fminf(fmaxf(fmaf(sys, iyp, cyo), 0.0f), yhi);
    else       yl = reflect_clipped(iyp) - by0f;

    const float xf = floorf(xl);
    const float yf = floorf(yl);
    const float fx = xl - xf;
    const float fy = yl - yf;
    const int xi = (int)xf;
    const int yi = (int)yf;

    const float gx1 = 1.0f - fx;
    const float gy1 = 1.0f - fy;
    const float w00 = gx1 * gy1;
    const float w01 = fx * gy1;
    const float w10 = gx1 * fy;
    const float w11 = fx * fy;

    const int i00 = yi * LSTRIDE + xi;          // all taps = imm offsets

    float acc0, acc1, acc2;
    {
        const float* s = smem + i00;
        acc0 = s[0] * w00 + s[1] * w01 + s[LSTRIDE] * w10 + s[LSTRIDE + 1] * w11;
        acc1 = s[CH_WORDS] * w00 + s[CH_WORDS + 1] * w01 +
               s[CH_WORDS + LSTRIDE] * w10 + s[CH_WORDS + LSTRIDE + 1] * w11;
        acc2 = s[2 * CH_WORDS] * w00 + s[2 * CH_WORDS + 1] * w01 +
               s[2 * CH_WORDS + LSTRIDE] * w10 + s[2 * CH_WORDS + LSTRIDE + 1] * w11;
    }

    float* ob = out + (size_t)b * (C_ * PLANE);
    const int ooff = (((blockIdx.y << 4) + lrow) << 9) + (blockIdx.x << 4) + lcol;
    ob[ooff] = acc0;
    ob[ooff + PLANE] = acc1;
    ob[ooff + 2 * PLANE] = acc2;
}

extern "C" void kernel_launch(void* const* d_in, const int* in_sizes, int n_in,
                              void* d_out, int out_size, void* d_ws, size_t ws_size,
                              hipStream_t stream) {
    const float* x = (const float*)d_in[0];
    const float* p = (const float*)d_in[1];
    float* out = (float*)d_out;

    dim3 block(256, 1, 1);
    dim3 grid(W_ / 16, H_ / 16, B_);
    st_kernel<<<grid, block, 0, stream>>>(x, p, out);
}